// Round 5
// baseline (380.849 us; speedup 1.0000x reference)
//
#include <hip/hip_runtime.h>
#include <cstdint>
#include <cstddef>

// ---------------------------------------------------------------------------
// 2-layer GAT on MI355X — bf16 features, single-pass softmax aggregation,
// software-pipelined gather loop, channel-split layer-1 aggregation.
//   CSR build (deg histogram -> scan -> atomicSub ticket fill)
//   pack W1/W2 -> MFMA frag-ready bf16
//   mfma_gemm<128,256>: h1b = x @ W1   (+ fused als/ald epilogue)
//   agg<1> grid.y=2: one-pass exp-weighted aggregation + b1 + ELU -> hactb
//   mfma_gemm<256,128>: h2b = hactb @ W2 (+ fused als/ald)
//   agg<2>: one-pass aggregation + head-mean + b2 + log_softmax -> d_out
// ---------------------------------------------------------------------------

typedef short bf16x8 __attribute__((ext_vector_type(8)));
typedef unsigned short u16x8 __attribute__((ext_vector_type(8)));
typedef float f32x4 __attribute__((ext_vector_type(4)));

__device__ inline unsigned short f2bf(float f) {
  unsigned u = __float_as_uint(f);
  unsigned r = (u + 0x7FFFu + ((u >> 16) & 1u)) >> 16;  // RNE
  return (unsigned short)r;
}
__device__ inline float bf2f(unsigned short s) {
  return __uint_as_float((unsigned)s << 16);
}
__device__ inline int imin(int a, int b) { return a < b ? a : b; }

// ------------------------------- CSR build ---------------------------------

__global__ __launch_bounds__(256) void detect_kernel(const int* __restrict__ words,
                                                     int E, int* __restrict__ flag) {
  int t = threadIdx.x;
  int n = E < 1024 ? E : 1024;
  int cnt = 0;
  for (int i = t; i < n; i += 256) cnt += (words[2 * i + 1] != 0) ? 1 : 0;
  for (int m = 1; m < 64; m <<= 1) cnt += __shfl_xor(cnt, m);
  if ((t & 63) == 0 && cnt) atomicAdd(flag, cnt);
}

__global__ __launch_bounds__(256) void extract_kernel(const void* __restrict__ ei,
                                                      int E, int N,
                                                      const int* __restrict__ flag,
                                                      int* __restrict__ src,
                                                      int* __restrict__ dst,
                                                      int* __restrict__ deg) {
  int e = blockIdx.x * 256 + threadIdx.x;
  int ET = E + N;
  if (e >= ET) return;
  int s, d;
  if (e < E) {
    if (flag[0] == 0) {  // int64
      const long long* p = (const long long*)ei;
      s = (int)p[e];
      d = (int)p[(size_t)E + e];
    } else {             // int32
      const int* p = (const int*)ei;
      s = p[e];
      d = p[E + e];
    }
  } else {
    s = d = e - E;  // self loop
  }
  src[e] = s;
  dst[e] = d;
  atomicAdd(&deg[d], 1);
}

__global__ __launch_bounds__(256) void scan_a(const int* __restrict__ deg,
                                              int* __restrict__ off,
                                              int* __restrict__ bsum, int N) {
  __shared__ int sh[256];
  int b = blockIdx.x, t = threadIdx.x;
  int base = b * 2048 + t * 8;
  int p[8];
  int run = 0;
#pragma unroll
  for (int j = 0; j < 8; ++j) {
    int v = (base + j < N) ? deg[base + j] : 0;
    run += v;
    p[j] = run;
  }
  sh[t] = run;
  __syncthreads();
  for (int d = 1; d < 256; d <<= 1) {
    int x = (t >= d) ? sh[t - d] : 0;
    __syncthreads();
    if (t >= d) sh[t] += x;
    __syncthreads();
  }
  int excl = sh[t] - run;
#pragma unroll
  for (int j = 0; j < 8; ++j)
    if (base + j < N) off[base + j + 1] = excl + p[j];
  if (t == 255) bsum[b] = sh[255];
}

__global__ void scan_b(int* __restrict__ bsum, int nb) {
  int run = 0;
  for (int i = 0; i < nb; ++i) {
    int v = bsum[i];
    bsum[i] = run;
    run += v;
  }
}

__global__ __launch_bounds__(256) void scan_c(int* __restrict__ off,
                                              const int* __restrict__ bsum, int N) {
  int i = blockIdx.x * 256 + threadIdx.x;
  if (i == 0) off[0] = 0;
  if (i >= 1 && i <= N) off[i] += bsum[(i - 1) / 2048];
}

// ticket via atomicSub on deg (deg dead after scan_a)
__global__ __launch_bounds__(256) void fill_kernel(const int* __restrict__ src,
                                                   const int* __restrict__ dst,
                                                   const int* __restrict__ off,
                                                   int* __restrict__ deg,
                                                   int* __restrict__ csr, int ET) {
  int e = blockIdx.x * 256 + threadIdx.x;
  if (e >= ET) return;
  int d = dst[e];
  int p = atomicSub(&deg[d], 1) - 1;
  csr[off[d] + p] = src[e];
}

// --------------------------- weight pre-pack -------------------------------
__global__ __launch_bounds__(256) void pack_kernel(const float* __restrict__ W,
                                                   short* __restrict__ Wp,
                                                   int NOUT, int total) {
  int NT = NOUT >> 4;
  for (int idx = blockIdx.x * 256 + threadIdx.x; idx < total;
       idx += gridDim.x * 256) {
    int j = idx & 7;
    int lane = (idx >> 3) & 63;
    int st = idx >> 9;
    int s = st / NT, t = st - s * NT;
    int k = s * 32 + (lane >> 4) * 8 + j;
    int n = t * 16 + (lane & 15);
    Wp[idx] = (short)f2bf(W[(size_t)k * NOUT + n]);
  }
}

// ------------------------------ MFMA GEMM + fused attention logits ---------
template <int K, int NOUT, bool AF32>
__global__ __launch_bounds__(256) void mfma_gemm(const void* __restrict__ Av,
                                                 const short* __restrict__ Bp,
                                                 short* __restrict__ Cb,
                                                 const float* __restrict__ as,
                                                 const float* __restrict__ ad,
                                                 float* __restrict__ alsO,
                                                 float* __restrict__ aldO, int M) {
  constexpr int KS = K / 32;
  constexpr int NT = NOUT / 16;
  constexpr int RST = NOUT + 8;  // padded LDS row stride (shorts)
  constexpr int C = NOUT / 8;    // channels per head
  __shared__ __align__(16) short lds[64 * RST];
  const int tid = threadIdx.x;
  const int wave = tid >> 6, lane = tid & 63;
  const int lo = lane & 15, hi = lane >> 4;
  const int rowA = blockIdx.x * 64 + wave * 16 + lo;
  const bool inb = rowA < M;

  f32x4 acc[NT];
#pragma unroll
  for (int t = 0; t < NT; ++t) acc[t] = (f32x4){0.f, 0.f, 0.f, 0.f};

#pragma unroll
  for (int s = 0; s < KS; ++s) {
    bf16x8 af;
    if constexpr (AF32) {
      const float* Ap = (const float*)Av;
      float v[8];
      if (inb) {
        const float4 x0 = *(const float4*)&Ap[(size_t)rowA * K + s * 32 + hi * 8];
        const float4 x1 = *(const float4*)&Ap[(size_t)rowA * K + s * 32 + hi * 8 + 4];
        v[0] = x0.x; v[1] = x0.y; v[2] = x0.z; v[3] = x0.w;
        v[4] = x1.x; v[5] = x1.y; v[6] = x1.z; v[7] = x1.w;
      } else {
#pragma unroll
        for (int j = 0; j < 8; ++j) v[j] = 0.f;
      }
#pragma unroll
      for (int j = 0; j < 8; ++j) af[j] = (short)f2bf(v[j]);
    } else {
      const short* Ab = (const short*)Av;
      if (inb) {
        af = *(const bf16x8*)&Ab[(size_t)rowA * K + s * 32 + hi * 8];
      } else {
#pragma unroll
        for (int j = 0; j < 8; ++j) af[j] = 0;
      }
    }
#pragma unroll
    for (int t = 0; t < NT; ++t) {
      bf16x8 bf = *(const bf16x8*)&Bp[((size_t)(s * NT + t) * 64 + lane) * 8];
      acc[t] = __builtin_amdgcn_mfma_f32_16x16x32_bf16(af, bf, acc[t], 0, 0, 0);
    }
  }

#pragma unroll
  for (int t = 0; t < NT; ++t)
#pragma unroll
    for (int r = 0; r < 4; ++r)
      lds[(wave * 16 + hi * 4 + r) * RST + t * 16 + lo] = (short)f2bf(acc[t][r]);
  __syncthreads();

  constexpr int VECS = 64 * NOUT / 8;
#pragma unroll
  for (int i = 0; i < VECS / 256; ++i) {
    int v = i * 256 + tid;
    int r = v / (NOUT / 8);
    int c = v % (NOUT / 8);
    int grow = blockIdx.x * 64 + r;
    if (grow < M)
      *(float4*)&Cb[(size_t)grow * NOUT + c * 8] =
          *(const float4*)&lds[r * RST + c * 8];
  }

  // fused al epilogue
  constexpr int SEGS = NOUT / 64;
  if (tid < 64 * SEGS) {
    int r = tid / SEGS, seg = tid % SEGS;
    int grow = blockIdx.x * 64 + r;
    float ps[8], pd[8];
#pragma unroll
    for (int k = 0; k < 8; ++k) { ps[k] = 0.f; pd[k] = 0.f; }
#pragma unroll
    for (int k = 0; k < 8; ++k) {
      int b = seg + SEGS * k;
      u16x8 u = *(const u16x8*)&lds[r * RST + b * 8];
#pragma unroll
      for (int j = 0; j < 8; ++j) {
        float hv = bf2f(u[j]);
        ps[k] = fmaf(hv, as[k * C + seg * 8 + j], ps[k]);
        pd[k] = fmaf(hv, ad[k * C + seg * 8 + j], pd[k]);
      }
    }
#pragma unroll
    for (int d = 1; d < SEGS; d <<= 1)
#pragma unroll
      for (int k = 0; k < 8; ++k) {
        ps[k] += __shfl_xor(ps[k], d);
        pd[k] += __shfl_xor(pd[k], d);
      }
    if (seg == 0 && grow < M) {
      *(float4*)&alsO[(size_t)grow * 8] = make_float4(ps[0], ps[1], ps[2], ps[3]);
      *(float4*)&alsO[(size_t)grow * 8 + 4] = make_float4(ps[4], ps[5], ps[6], ps[7]);
      *(float4*)&aldO[(size_t)grow * 8] = make_float4(pd[0], pd[1], pd[2], pd[3]);
      *(float4*)&aldO[(size_t)grow * 8 + 4] = make_float4(pd[4], pd[5], pd[6], pd[7]);
    }
  }
}

// ------------------------------ aggregation --------------------------------
// One wave per (dst node, channel-block). 16 lanes per edge (128 bf16 ch),
// NS=4 edge streams, 2x unroll, csr+als software-pipelined one iteration
// ahead (rotated registers; bounds via clamp-to-last + weight zeroing).
// Single pass, no max subtraction (logits bounded, softmax shift-invariant).
template <int LAYER>
__global__ __launch_bounds__(256) void agg_kernel(const short* __restrict__ hb,
                                                  const float* __restrict__ als,
                                                  const float* __restrict__ ald,
                                                  const int* __restrict__ off,
                                                  const int* __restrict__ csr,
                                                  const float* __restrict__ bias,
                                                  void* __restrict__ outv, int N) {
  constexpr int ROWCH = (LAYER == 1) ? 256 : 128;  // bf16 channels per row
  constexpr int HC = (LAYER == 1) ? 32 : 16;       // channels per head
  constexpr int LPG = 16;                          // lanes per edge
  constexpr int NS = 4;                            // edge streams
  int wid = blockIdx.x * 4 + (threadIdx.x >> 6);
  if (wid >= N) return;
  int cb = blockIdx.y;  // channel block (0..1 for L1, 0 for L2)
  int lane = threadIdx.x & 63;
  int es = lane >> 4;           // edge stream
  int gl = lane & (LPG - 1);    // lane within group
  int chbase = cb * 128 + gl * 8;
  int head = chbase / HC;
  int rs = off[wid], re = off[wid + 1];
  int relast = re - 1;
  float aldv = ald[wid * 8 + head];

  float acc[8];
#pragma unroll
  for (int j = 0; j < 8; ++j) acc[j] = 0.f;
  float ws = 0.f;

  int i0 = rs + es;
  int s0 = csr[imin(i0, relast)];
  int s1 = csr[imin(i0 + NS, relast)];
  float a0 = als[s0 * 8 + head];
  float a1 = als[s1 * 8 + head];

  for (int i = i0; i < re; i += 2 * NS) {
    // issue current row gathers immediately
    u16x8 u0 = *(const u16x8*)&hb[s0 * ROWCH + chbase];
    u16x8 u1 = *(const u16x8*)&hb[s1 * ROWCH + chbase];
    // prefetch next iteration's indices and logits
    int sn0 = csr[imin(i + 2 * NS, relast)];
    int sn1 = csr[imin(i + 3 * NS, relast)];
    float an0 = als[sn0 * 8 + head];
    float an1 = als[sn1 * 8 + head];
    // weights for current pair
    float e0 = a0 + aldv;
    float e1 = a1 + aldv;
    e0 = e0 > 0.f ? e0 : 0.2f * e0;
    e1 = e1 > 0.f ? e1 : 0.2f * e1;
    float w0 = __expf(e0);
    float w1 = (i + NS < re) ? __expf(e1) : 0.f;
    ws += w0 + w1;
#pragma unroll
    for (int j = 0; j < 8; ++j)
      acc[j] = fmaf(w1, bf2f(u1[j]), fmaf(w0, bf2f(u0[j]), acc[j]));
    s0 = sn0; s1 = sn1; a0 = an0; a1 = an1;
  }

  // combine edge streams (xor over stream bits)
#pragma unroll
  for (int d = LPG; d < 64; d <<= 1) {
    ws += __shfl_xor(ws, d);
#pragma unroll
    for (int j = 0; j < 8; ++j) acc[j] += __shfl_xor(acc[j], d);
  }
  float inv = 1.f / ws;

  if constexpr (LAYER == 1) {
    if (lane < LPG) {
      u16x8 o;
#pragma unroll
      for (int j = 0; j < 8; ++j) {
        float v = acc[j] * inv + bias[chbase + j];
        o[j] = f2bf(v > 0.f ? v : expm1f(v));  // ELU
      }
      *(u16x8*)&((short*)outv)[wid * 256 + chbase] = o;
    }
  } else {
    // normalize, then mean over heads (gl = 2h + p), log_softmax over 16 ch
#pragma unroll
    for (int j = 0; j < 8; ++j) acc[j] *= inv;
#pragma unroll
    for (int d = 2; d <= 8; d <<= 1)
#pragma unroll
      for (int j = 0; j < 8; ++j) acc[j] += __shfl_xor(acc[j], d);
    int p = gl & 1;
    float v[8];
#pragma unroll
    for (int j = 0; j < 8; ++j) v[j] = acc[j] * 0.125f + bias[p * 8 + j];
    float m = v[0];
#pragma unroll
    for (int j = 1; j < 8; ++j) m = fmaxf(m, v[j]);
    m = fmaxf(m, __shfl_xor(m, 1));
    float se = 0.f;
#pragma unroll
    for (int j = 0; j < 8; ++j) se += __expf(v[j] - m);
    se += __shfl_xor(se, 1);
    float lse = m + logf(se);
    if (lane < 2) {
      float* out = (float*)outv;
      *(float4*)&out[(size_t)wid * 16 + p * 8] =
          make_float4(v[0] - lse, v[1] - lse, v[2] - lse, v[3] - lse);
      *(float4*)&out[(size_t)wid * 16 + p * 8 + 4] =
          make_float4(v[4] - lse, v[5] - lse, v[6] - lse, v[7] - lse);
    }
  }
}

// ---------------------------------------------------------------------------

extern "C" void kernel_launch(void* const* d_in, const int* in_sizes, int n_in,
                              void* d_out, int out_size, void* d_ws, size_t ws_size,
                              hipStream_t stream) {
  const float* x = (const float*)d_in[0];
  const void* ei = d_in[1];
  const float* W1 = (const float*)d_in[2];
  const float* as1 = (const float*)d_in[3];
  const float* ad1 = (const float*)d_in[4];
  const float* b1 = (const float*)d_in[5];
  const float* W2 = (const float*)d_in[6];
  const float* as2 = (const float*)d_in[7];
  const float* ad2 = (const float*)d_in[8];
  const float* b2 = (const float*)d_in[9];
  float* out = (float*)d_out;

  const int N = out_size / 16;    // 100000
  const int E = in_sizes[1] / 2;  // 800000
  const int ET = E + N;

  char* p = (char*)d_ws;
  auto alloc = [&](size_t bytes) {
    char* r = p;
    p += (bytes + 255) & ~(size_t)255;
    return (void*)r;
  };
  short* h1b = (short*)alloc((size_t)N * 256 * 2);
  short* hactb = (short*)alloc((size_t)N * 256 * 2);
  float* als = (float*)alloc((size_t)N * 8 * 4);
  float* ald = (float*)alloc((size_t)N * 8 * 4);
  int* src32 = (int*)alloc((size_t)ET * 4);
  int* dst32 = (int*)alloc((size_t)ET * 4);
  int* csr = (int*)alloc((size_t)ET * 4);
  int* deg = (int*)alloc((size_t)N * 4);
  int* off = (int*)alloc((size_t)(N + 1) * 4);
  int* bsum = (int*)alloc(256 * 4);
  int* flag = (int*)alloc(256);
  short* W1p = (short*)alloc(128 * 256 * 2);
  short* W2p = (short*)alloc(256 * 128 * 2);
  short* h2b = h1b;  // h1b dead after agg<1>

  hipMemsetAsync(deg, 0, (size_t)N * 4, stream);
  hipMemsetAsync(flag, 0, 4, stream);

  detect_kernel<<<1, 256, 0, stream>>>((const int*)ei, E, flag);
  int gridET = (ET + 255) / 256;
  extract_kernel<<<gridET, 256, 0, stream>>>(ei, E, N, flag, src32, dst32, deg);
  int nscan = (N + 2047) / 2048;
  scan_a<<<nscan, 256, 0, stream>>>(deg, off, bsum, N);
  scan_b<<<1, 1, 0, stream>>>(bsum, nscan);
  scan_c<<<(N + 256) / 256, 256, 0, stream>>>(off, bsum, N);
  fill_kernel<<<gridET, 256, 0, stream>>>(src32, dst32, off, deg, csr, ET);

  pack_kernel<<<128, 256, 0, stream>>>(W1, W1p, 256, 128 * 256);
  pack_kernel<<<128, 256, 0, stream>>>(W2, W2p, 128, 256 * 128);

  int gemmGrid = (N + 63) / 64;
  int nodeGrid = (N + 3) / 4;

  mfma_gemm<128, 256, true>
      <<<gemmGrid, 256, 0, stream>>>(x, W1p, h1b, as1, ad1, als, ald, N);
  agg_kernel<1><<<dim3(nodeGrid, 2), 256, 0, stream>>>(h1b, als, ald, off, csr,
                                                       b1, hactb, N);
  mfma_gemm<256, 128, false>
      <<<gemmGrid, 256, 0, stream>>>(hactb, W2p, h2b, as2, ad2, als, ald, N);
  agg_kernel<2><<<dim3(nodeGrid, 1), 256, 0, stream>>>(h2b, als, ald, off, csr,
                                                       b2, out, N);
}

// Round 6
// 377.410 us; speedup vs baseline: 1.0091x; 1.0091x over previous
//
#include <hip/hip_runtime.h>
#include <cstdint>
#include <cstddef>

// ---------------------------------------------------------------------------
// 2-layer GAT on MI355X — bf16 features, precomputed edge weights, slim
// single-pass aggregation (round-4 structure + w-precompute).
//   CSR build: deg histogram -> scan -> atomicSub ticket fill (csr + dstc)
//   pack W1/W2 -> MFMA frag-ready bf16
//   mfma_gemm<128,256>: h1b = x @ W1   (+ fused als/ald epilogue)
//   wpre: w[pos,h] = exp(leakyrelu(als[src]+ald[dst]))  (edge-parallel)
//   agg<1>: acc += w*h gather, ws += w; normalize; + b1 + ELU -> hactb
//   mfma_gemm<256,128>: h2b = hactb @ W2 (+ fused als/ald)
//   wpre; agg<2>: + head-mean + b2 + log_softmax -> d_out
// ---------------------------------------------------------------------------

typedef short bf16x8 __attribute__((ext_vector_type(8)));
typedef unsigned short u16x8 __attribute__((ext_vector_type(8)));
typedef float f32x4 __attribute__((ext_vector_type(4)));

__device__ inline unsigned short f2bf(float f) {
  unsigned u = __float_as_uint(f);
  unsigned r = (u + 0x7FFFu + ((u >> 16) & 1u)) >> 16;  // RNE
  return (unsigned short)r;
}
__device__ inline float bf2f(unsigned short s) {
  return __uint_as_float((unsigned)s << 16);
}

// ------------------------------- CSR build ---------------------------------

__global__ __launch_bounds__(256) void detect_kernel(const int* __restrict__ words,
                                                     int E, int* __restrict__ flag) {
  int t = threadIdx.x;
  int n = E < 1024 ? E : 1024;
  int cnt = 0;
  for (int i = t; i < n; i += 256) cnt += (words[2 * i + 1] != 0) ? 1 : 0;
  for (int m = 1; m < 64; m <<= 1) cnt += __shfl_xor(cnt, m);
  if ((t & 63) == 0 && cnt) atomicAdd(flag, cnt);
}

__global__ __launch_bounds__(256) void extract_kernel(const void* __restrict__ ei,
                                                      int E, int N,
                                                      const int* __restrict__ flag,
                                                      int* __restrict__ src,
                                                      int* __restrict__ dst,
                                                      int* __restrict__ deg) {
  int e = blockIdx.x * 256 + threadIdx.x;
  int ET = E + N;
  if (e >= ET) return;
  int s, d;
  if (e < E) {
    if (flag[0] == 0) {  // int64
      const long long* p = (const long long*)ei;
      s = (int)p[e];
      d = (int)p[(size_t)E + e];
    } else {             // int32
      const int* p = (const int*)ei;
      s = p[e];
      d = p[E + e];
    }
  } else {
    s = d = e - E;  // self loop
  }
  src[e] = s;
  dst[e] = d;
  atomicAdd(&deg[d], 1);
}

__global__ __launch_bounds__(256) void scan_a(const int* __restrict__ deg,
                                              int* __restrict__ off,
                                              int* __restrict__ bsum, int N) {
  __shared__ int sh[256];
  int b = blockIdx.x, t = threadIdx.x;
  int base = b * 2048 + t * 8;
  int p[8];
  int run = 0;
#pragma unroll
  for (int j = 0; j < 8; ++j) {
    int v = (base + j < N) ? deg[base + j] : 0;
    run += v;
    p[j] = run;
  }
  sh[t] = run;
  __syncthreads();
  for (int d = 1; d < 256; d <<= 1) {
    int x = (t >= d) ? sh[t - d] : 0;
    __syncthreads();
    if (t >= d) sh[t] += x;
    __syncthreads();
  }
  int excl = sh[t] - run;
#pragma unroll
  for (int j = 0; j < 8; ++j)
    if (base + j < N) off[base + j + 1] = excl + p[j];
  if (t == 255) bsum[b] = sh[255];
}

// one-wave exclusive scan of <=64 block sums
__global__ void scan_b(int* __restrict__ bsum, int nb) {
  int t = threadIdx.x;
  int orig = (t < nb) ? bsum[t] : 0;
  int v = orig;
  for (int d = 1; d < 64; d <<= 1) {
    int u = __shfl_up(v, d);
    if (t >= d) v += u;
  }
  if (t < nb) bsum[t] = v - orig;
}

__global__ __launch_bounds__(256) void scan_c(int* __restrict__ off,
                                              const int* __restrict__ bsum, int N) {
  int i = blockIdx.x * 256 + threadIdx.x;
  if (i == 0) off[0] = 0;
  if (i >= 1 && i <= N) off[i] += bsum[(i - 1) / 2048];
}

// ticket via atomicSub on deg (deg dead after scan_a); writes csr + dstc
__global__ __launch_bounds__(256) void fill_kernel(const int* __restrict__ src,
                                                   const int* __restrict__ dst,
                                                   const int* __restrict__ off,
                                                   int* __restrict__ deg,
                                                   int* __restrict__ csr,
                                                   int* __restrict__ dstc, int ET) {
  int e = blockIdx.x * 256 + threadIdx.x;
  if (e >= ET) return;
  int d = dst[e];
  int p = atomicSub(&deg[d], 1) - 1;
  int pos = off[d] + p;
  csr[pos] = src[e];
  dstc[pos] = d;
}

// --------------------------- weight pre-pack -------------------------------
__global__ __launch_bounds__(256) void pack_kernel(const float* __restrict__ W,
                                                   short* __restrict__ Wp,
                                                   int NOUT, int total) {
  int NT = NOUT >> 4;
  for (int idx = blockIdx.x * 256 + threadIdx.x; idx < total;
       idx += gridDim.x * 256) {
    int j = idx & 7;
    int lane = (idx >> 3) & 63;
    int st = idx >> 9;
    int s = st / NT, t = st - s * NT;
    int k = s * 32 + (lane >> 4) * 8 + j;
    int n = t * 16 + (lane & 15);
    Wp[idx] = (short)f2bf(W[(size_t)k * NOUT + n]);
  }
}

// ------------------------------ MFMA GEMM + fused attention logits ---------
template <int K, int NOUT, bool AF32>
__global__ __launch_bounds__(256) void mfma_gemm(const void* __restrict__ Av,
                                                 const short* __restrict__ Bp,
                                                 short* __restrict__ Cb,
                                                 const float* __restrict__ as,
                                                 const float* __restrict__ ad,
                                                 float* __restrict__ alsO,
                                                 float* __restrict__ aldO, int M) {
  constexpr int KS = K / 32;
  constexpr int NT = NOUT / 16;
  constexpr int RST = NOUT + 8;  // padded LDS row stride (shorts)
  constexpr int C = NOUT / 8;    // channels per head
  __shared__ __align__(16) short lds[64 * RST];
  const int tid = threadIdx.x;
  const int wave = tid >> 6, lane = tid & 63;
  const int lo = lane & 15, hi = lane >> 4;
  const int rowA = blockIdx.x * 64 + wave * 16 + lo;
  const bool inb = rowA < M;

  f32x4 acc[NT];
#pragma unroll
  for (int t = 0; t < NT; ++t) acc[t] = (f32x4){0.f, 0.f, 0.f, 0.f};

#pragma unroll
  for (int s = 0; s < KS; ++s) {
    bf16x8 af;
    if constexpr (AF32) {
      const float* Ap = (const float*)Av;
      float v[8];
      if (inb) {
        const float4 x0 = *(const float4*)&Ap[(size_t)rowA * K + s * 32 + hi * 8];
        const float4 x1 = *(const float4*)&Ap[(size_t)rowA * K + s * 32 + hi * 8 + 4];
        v[0] = x0.x; v[1] = x0.y; v[2] = x0.z; v[3] = x0.w;
        v[4] = x1.x; v[5] = x1.y; v[6] = x1.z; v[7] = x1.w;
      } else {
#pragma unroll
        for (int j = 0; j < 8; ++j) v[j] = 0.f;
      }
#pragma unroll
      for (int j = 0; j < 8; ++j) af[j] = (short)f2bf(v[j]);
    } else {
      const short* Ab = (const short*)Av;
      if (inb) {
        af = *(const bf16x8*)&Ab[(size_t)rowA * K + s * 32 + hi * 8];
      } else {
#pragma unroll
        for (int j = 0; j < 8; ++j) af[j] = 0;
      }
    }
#pragma unroll
    for (int t = 0; t < NT; ++t) {
      bf16x8 bf = *(const bf16x8*)&Bp[((size_t)(s * NT + t) * 64 + lane) * 8];
      acc[t] = __builtin_amdgcn_mfma_f32_16x16x32_bf16(af, bf, acc[t], 0, 0, 0);
    }
  }

#pragma unroll
  for (int t = 0; t < NT; ++t)
#pragma unroll
    for (int r = 0; r < 4; ++r)
      lds[(wave * 16 + hi * 4 + r) * RST + t * 16 + lo] = (short)f2bf(acc[t][r]);
  __syncthreads();

  constexpr int VECS = 64 * NOUT / 8;
#pragma unroll
  for (int i = 0; i < VECS / 256; ++i) {
    int v = i * 256 + tid;
    int r = v / (NOUT / 8);
    int c = v % (NOUT / 8);
    int grow = blockIdx.x * 64 + r;
    if (grow < M)
      *(float4*)&Cb[(size_t)grow * NOUT + c * 8] =
          *(const float4*)&lds[r * RST + c * 8];
  }

  // fused al epilogue
  constexpr int SEGS = NOUT / 64;
  if (tid < 64 * SEGS) {
    int r = tid / SEGS, seg = tid % SEGS;
    int grow = blockIdx.x * 64 + r;
    float ps[8], pd[8];
#pragma unroll
    for (int k = 0; k < 8; ++k) { ps[k] = 0.f; pd[k] = 0.f; }
#pragma unroll
    for (int k = 0; k < 8; ++k) {
      int b = seg + SEGS * k;
      u16x8 u = *(const u16x8*)&lds[r * RST + b * 8];
#pragma unroll
      for (int j = 0; j < 8; ++j) {
        float hv = bf2f(u[j]);
        ps[k] = fmaf(hv, as[k * C + seg * 8 + j], ps[k]);
        pd[k] = fmaf(hv, ad[k * C + seg * 8 + j], pd[k]);
      }
    }
#pragma unroll
    for (int d = 1; d < SEGS; d <<= 1)
#pragma unroll
      for (int k = 0; k < 8; ++k) {
        ps[k] += __shfl_xor(ps[k], d);
        pd[k] += __shfl_xor(pd[k], d);
      }
    if (seg == 0 && grow < M) {
      *(float4*)&alsO[(size_t)grow * 8] = make_float4(ps[0], ps[1], ps[2], ps[3]);
      *(float4*)&alsO[(size_t)grow * 8 + 4] = make_float4(ps[4], ps[5], ps[6], ps[7]);
      *(float4*)&aldO[(size_t)grow * 8] = make_float4(pd[0], pd[1], pd[2], pd[3]);
      *(float4*)&aldO[(size_t)grow * 8 + 4] = make_float4(pd[4], pd[5], pd[6], pd[7]);
    }
  }
}

// --------------------------- edge weight precompute ------------------------
// w[pos*8+h] = exp(leakyrelu(als[src,h] + ald[dst,h])); edge-parallel,
// coalesced; no max subtraction (logits bounded, softmax shift-invariant).
__global__ __launch_bounds__(256) void wpre_kernel(const int* __restrict__ csr,
                                                   const int* __restrict__ dstc,
                                                   const float* __restrict__ als,
                                                   const float* __restrict__ ald,
                                                   float* __restrict__ w, int ET8) {
  int idx = blockIdx.x * 256 + threadIdx.x;
  if (idx >= ET8) return;
  int pos = idx >> 3, h = idx & 7;
  int s = csr[pos], d = dstc[pos];
  float e = als[s * 8 + h] + ald[d * 8 + h];
  e = e > 0.f ? e : 0.2f * e;
  w[idx] = __expf(e);
}

// ------------------------------ aggregation --------------------------------
// One wave per dst node; LPG lanes per edge, NS streams, 2x unroll. Inner
// loop: csr -> hb gather + independent coalesced w load. Normalize at end.
template <int LAYER>
__global__ __launch_bounds__(256) void agg_kernel(const short* __restrict__ hb,
                                                  const float* __restrict__ w,
                                                  const int* __restrict__ off,
                                                  const int* __restrict__ csr,
                                                  const float* __restrict__ bias,
                                                  void* __restrict__ outv, int N) {
  constexpr int HC = (LAYER == 1) ? 32 : 16;  // channels per head
  constexpr int ROW = (LAYER == 1) ? 256 : 128;
  constexpr int LPG = ROW / 8;   // lanes per edge (32 / 16)
  constexpr int NS = 64 / LPG;   // edge streams (2 / 4)
  int wid = blockIdx.x * 4 + (threadIdx.x >> 6);
  if (wid >= N) return;
  int lane = threadIdx.x & 63;
  int rs = off[wid], re = off[wid + 1];
  int es = lane / LPG;
  int gl = lane & (LPG - 1);
  int head = (gl * 8) / HC;

  float acc[8];
#pragma unroll
  for (int j = 0; j < 8; ++j) acc[j] = 0.f;
  float ws = 0.f;

  int i = rs + es;
  for (; i + NS < re; i += 2 * NS) {
    int s0 = csr[i], s1 = csr[i + NS];
    float w0 = w[i * 8 + head];
    float w1 = w[(i + NS) * 8 + head];
    u16x8 u0 = *(const u16x8*)&hb[(size_t)s0 * ROW + gl * 8];
    u16x8 u1 = *(const u16x8*)&hb[(size_t)s1 * ROW + gl * 8];
    ws += w0 + w1;
#pragma unroll
    for (int j = 0; j < 8; ++j)
      acc[j] = fmaf(w1, bf2f(u1[j]), fmaf(w0, bf2f(u0[j]), acc[j]));
  }
  if (i < re) {
    int s0 = csr[i];
    float w0 = w[i * 8 + head];
    u16x8 u0 = *(const u16x8*)&hb[(size_t)s0 * ROW + gl * 8];
    ws += w0;
#pragma unroll
    for (int j = 0; j < 8; ++j) acc[j] = fmaf(w0, bf2f(u0[j]), acc[j]);
  }

  // combine edge streams
#pragma unroll
  for (int d = LPG; d < 64; d <<= 1) {
    ws += __shfl_xor(ws, d);
#pragma unroll
    for (int j = 0; j < 8; ++j) acc[j] += __shfl_xor(acc[j], d);
  }
  float inv = 1.f / ws;

  if constexpr (LAYER == 1) {
    if (lane < LPG) {
      u16x8 o;
#pragma unroll
      for (int j = 0; j < 8; ++j) {
        float v = acc[j] * inv + bias[gl * 8 + j];
        o[j] = f2bf(v > 0.f ? v : expm1f(v));  // ELU
      }
      *(u16x8*)&((short*)outv)[(size_t)wid * 256 + gl * 8] = o;
    }
  } else {
    // normalize, mean over heads (gl = 2h + p), log_softmax over 16 channels
#pragma unroll
    for (int j = 0; j < 8; ++j) acc[j] *= inv;
#pragma unroll
    for (int d = 2; d <= 8; d <<= 1)
#pragma unroll
      for (int j = 0; j < 8; ++j) acc[j] += __shfl_xor(acc[j], d);
    int p = gl & 1;
    float v[8];
#pragma unroll
    for (int j = 0; j < 8; ++j) v[j] = acc[j] * 0.125f + bias[p * 8 + j];
    float m = v[0];
#pragma unroll
    for (int j = 1; j < 8; ++j) m = fmaxf(m, v[j]);
    m = fmaxf(m, __shfl_xor(m, 1));
    float se = 0.f;
#pragma unroll
    for (int j = 0; j < 8; ++j) se += __expf(v[j] - m);
    se += __shfl_xor(se, 1);
    float lse = m + logf(se);
    if (lane < 2) {
      float* out = (float*)outv;
      *(float4*)&out[(size_t)wid * 16 + p * 8] =
          make_float4(v[0] - lse, v[1] - lse, v[2] - lse, v[3] - lse);
      *(float4*)&out[(size_t)wid * 16 + p * 8 + 4] =
          make_float4(v[4] - lse, v[5] - lse, v[6] - lse, v[7] - lse);
    }
  }
}

// ---------------------------------------------------------------------------

extern "C" void kernel_launch(void* const* d_in, const int* in_sizes, int n_in,
                              void* d_out, int out_size, void* d_ws, size_t ws_size,
                              hipStream_t stream) {
  const float* x = (const float*)d_in[0];
  const void* ei = d_in[1];
  const float* W1 = (const float*)d_in[2];
  const float* as1 = (const float*)d_in[3];
  const float* ad1 = (const float*)d_in[4];
  const float* b1 = (const float*)d_in[5];
  const float* W2 = (const float*)d_in[6];
  const float* as2 = (const float*)d_in[7];
  const float* ad2 = (const float*)d_in[8];
  const float* b2 = (const float*)d_in[9];
  float* out = (float*)d_out;

  const int N = out_size / 16;    // 100000
  const int E = in_sizes[1] / 2;  // 800000
  const int ET = E + N;

  char* p = (char*)d_ws;
  auto alloc = [&](size_t bytes) {
    char* r = p;
    p += (bytes + 255) & ~(size_t)255;
    return (void*)r;
  };
  short* h1b = (short*)alloc((size_t)N * 256 * 2);
  short* hactb = (short*)alloc((size_t)N * 256 * 2);
  float* als = (float*)alloc((size_t)N * 8 * 4);
  float* ald = (float*)alloc((size_t)N * 8 * 4);
  float* w = (float*)alloc((size_t)ET * 8 * 4);
  int* src32 = (int*)alloc((size_t)ET * 4);
  int* dst32 = (int*)alloc((size_t)ET * 4);
  int* csr = (int*)alloc((size_t)ET * 4);
  int* dstc = (int*)alloc((size_t)ET * 4);
  int* deg = (int*)alloc((size_t)N * 4);
  int* off = (int*)alloc((size_t)(N + 1) * 4);
  int* bsum = (int*)alloc(256 * 4);
  int* flag = (int*)alloc(256);
  short* W1p = (short*)alloc(128 * 256 * 2);
  short* W2p = (short*)alloc(256 * 128 * 2);
  short* h2b = h1b;  // h1b dead after agg<1>

  hipMemsetAsync(deg, 0, (size_t)N * 4, stream);
  hipMemsetAsync(flag, 0, 4, stream);

  detect_kernel<<<1, 256, 0, stream>>>((const int*)ei, E, flag);
  int gridET = (ET + 255) / 256;
  extract_kernel<<<gridET, 256, 0, stream>>>(ei, E, N, flag, src32, dst32, deg);
  int nscan = (N + 2047) / 2048;
  scan_a<<<nscan, 256, 0, stream>>>(deg, off, bsum, N);
  scan_b<<<1, 64, 0, stream>>>(bsum, nscan);
  scan_c<<<(N + 256) / 256, 256, 0, stream>>>(off, bsum, N);
  fill_kernel<<<gridET, 256, 0, stream>>>(src32, dst32, off, deg, csr, dstc, ET);

  pack_kernel<<<128, 256, 0, stream>>>(W1, W1p, 256, 128 * 256);
  pack_kernel<<<128, 256, 0, stream>>>(W2, W2p, 128, 256 * 128);

  int gemmGrid = (N + 63) / 64;
  int nodeGrid = (N + 3) / 4;
  int ET8 = ET * 8;
  int wGrid = (ET8 + 255) / 256;

  mfma_gemm<128, 256, true>
      <<<gemmGrid, 256, 0, stream>>>(x, W1p, h1b, as1, ad1, als, ald, N);
  wpre_kernel<<<wGrid, 256, 0, stream>>>(csr, dstc, als, ald, w, ET8);
  agg_kernel<1><<<nodeGrid, 256, 0, stream>>>(h1b, w, off, csr, b1, hactb, N);
  mfma_gemm<256, 128, false>
      <<<gemmGrid, 256, 0, stream>>>(hactb, W2p, h2b, as2, ad2, als, ald, N);
  wpre_kernel<<<wGrid, 256, 0, stream>>>(csr, dstc, als, ald, w, ET8);
  agg_kernel<2><<<nodeGrid, 256, 0, stream>>>(h2b, w, off, csr, b2, out, N);
}

// Round 8
// 338.476 us; speedup vs baseline: 1.1252x; 1.1150x over previous
//
#include <hip/hip_runtime.h>
#include <cstdint>
#include <cstddef>

// ---------------------------------------------------------------------------
// 2-layer GAT on MI355X — round-4 structure + fp8(e4m3fn) layer-1 value rows.
//   CSR build: deg histogram -> scan -> atomicSub ticket fill
//   pack W1/W2 -> MFMA frag-ready bf16
//   mfma_gemm<128,256,f32A,FP8out>: h1q(fp8) = x @ W1 (+ fused f32-precision
//        als/ald epilogue from the bf16 LDS tile)
//   agg1: one-pass exp-weighted fp8 gather + b1 + ELU -> hactb (bf16)
//   mfma_gemm<256,128,bf16A,bf16out>: h2b = hactb @ W2 (+ fused als/ald)
//   agg2: one-pass bf16 gather + head-mean + b2 + log_softmax -> d_out
// ---------------------------------------------------------------------------

typedef short bf16x8 __attribute__((ext_vector_type(8)));
typedef unsigned short u16x8 __attribute__((ext_vector_type(8)));
typedef float f32x4 __attribute__((ext_vector_type(4)));

__device__ inline unsigned short f2bf(float f) {
  unsigned u = __float_as_uint(f);
  unsigned r = (u + 0x7FFFu + ((u >> 16) & 1u)) >> 16;  // RNE
  return (unsigned short)r;
}
__device__ inline float bf2f(unsigned short s) {
  return __uint_as_float((unsigned)s << 16);
}

// ---- OCP e4m3fn helpers ----------------------------------------------------
// encode: RNE, clamp to +-448 (avoids NaN pattern 0x7F)
__device__ inline unsigned char fp8enc(float x) {
  unsigned u = __float_as_uint(x);
  unsigned s = u >> 31;
  float ax = fminf(fabsf(x), 448.f);
  unsigned em;
  if (ax >= 0.015625f) {  // >= 2^-6: normal
    unsigned b = __float_as_uint(ax);
    unsigned b2 = b + 0x7FFFFu + ((b >> 20) & 1u);  // RNE to 3 mantissa bits
    em = (b2 >> 20) - 960u;                         // (e32-120)<<3 | m3
    if (em > 126u) em = 126u;                       // clamp to 448
  } else {                                          // denormal: m * 2^-9
    em = (unsigned)__float2int_rn(ax * 512.f);
  }
  return (unsigned char)((s << 7) | em);
}
// manual decode of one byte (fallback path)
__device__ inline float fp8dec_sw(unsigned b8) {
  unsigned s = b8 >> 7, em = b8 & 0x7Fu;
  float fn = __uint_as_float((s << 31) | ((em + 960u) << 20));
  float fd = (float)em * 0.001953125f;  // m * 2^-9
  fd = s ? -fd : fd;
  return em >= 8u ? fn : fd;
}
// decode all 4 bytes of dword w into out[0..3] (byte-select must be literal)
__device__ inline void fp8dec4(unsigned w, float* out) {
#if __has_builtin(__builtin_amdgcn_cvt_f32_fp8)
  out[0] = __builtin_amdgcn_cvt_f32_fp8(w, 0);
  out[1] = __builtin_amdgcn_cvt_f32_fp8(w, 1);
  out[2] = __builtin_amdgcn_cvt_f32_fp8(w, 2);
  out[3] = __builtin_amdgcn_cvt_f32_fp8(w, 3);
#else
  out[0] = fp8dec_sw(w & 0xFFu);
  out[1] = fp8dec_sw((w >> 8) & 0xFFu);
  out[2] = fp8dec_sw((w >> 16) & 0xFFu);
  out[3] = fp8dec_sw((w >> 24) & 0xFFu);
#endif
}

// ------------------------------- CSR build ---------------------------------

__global__ __launch_bounds__(256) void detect_kernel(const int* __restrict__ words,
                                                     int E, int* __restrict__ flag) {
  int t = threadIdx.x;
  int n = E < 1024 ? E : 1024;
  int cnt = 0;
  for (int i = t; i < n; i += 256) cnt += (words[2 * i + 1] != 0) ? 1 : 0;
  for (int m = 1; m < 64; m <<= 1) cnt += __shfl_xor(cnt, m);
  if ((t & 63) == 0 && cnt) atomicAdd(flag, cnt);
}

__global__ __launch_bounds__(256) void extract_kernel(const void* __restrict__ ei,
                                                      int E, int N,
                                                      const int* __restrict__ flag,
                                                      int* __restrict__ src,
                                                      int* __restrict__ dst,
                                                      int* __restrict__ deg) {
  int e = blockIdx.x * 256 + threadIdx.x;
  int ET = E + N;
  if (e >= ET) return;
  int s, d;
  if (e < E) {
    if (flag[0] == 0) {  // int64
      const long long* p = (const long long*)ei;
      s = (int)p[e];
      d = (int)p[(size_t)E + e];
    } else {             // int32
      const int* p = (const int*)ei;
      s = p[e];
      d = p[E + e];
    }
  } else {
    s = d = e - E;  // self loop
  }
  src[e] = s;
  dst[e] = d;
  atomicAdd(&deg[d], 1);
}

__global__ __launch_bounds__(256) void scan_a(const int* __restrict__ deg,
                                              int* __restrict__ off,
                                              int* __restrict__ bsum, int N) {
  __shared__ int sh[256];
  int b = blockIdx.x, t = threadIdx.x;
  int base = b * 2048 + t * 8;
  int p[8];
  int run = 0;
#pragma unroll
  for (int j = 0; j < 8; ++j) {
    int v = (base + j < N) ? deg[base + j] : 0;
    run += v;
    p[j] = run;
  }
  sh[t] = run;
  __syncthreads();
  for (int d = 1; d < 256; d <<= 1) {
    int x = (t >= d) ? sh[t - d] : 0;
    __syncthreads();
    if (t >= d) sh[t] += x;
    __syncthreads();
  }
  int excl = sh[t] - run;
#pragma unroll
  for (int j = 0; j < 8; ++j)
    if (base + j < N) off[base + j + 1] = excl + p[j];
  if (t == 255) bsum[b] = sh[255];
}

// one-wave exclusive scan of <=64 block sums
__global__ void scan_b(int* __restrict__ bsum, int nb) {
  int t = threadIdx.x;
  int orig = (t < nb) ? bsum[t] : 0;
  int v = orig;
  for (int d = 1; d < 64; d <<= 1) {
    int u = __shfl_up(v, d);
    if (t >= d) v += u;
  }
  if (t < nb) bsum[t] = v - orig;
}

__global__ __launch_bounds__(256) void scan_c(int* __restrict__ off,
                                              const int* __restrict__ bsum, int N) {
  int i = blockIdx.x * 256 + threadIdx.x;
  if (i == 0) off[0] = 0;
  if (i >= 1 && i <= N) off[i] += bsum[(i - 1) / 2048];
}

// ticket via atomicSub on deg (deg dead after scan_a)
__global__ __launch_bounds__(256) void fill_kernel(const int* __restrict__ src,
                                                   const int* __restrict__ dst,
                                                   const int* __restrict__ off,
                                                   int* __restrict__ deg,
                                                   int* __restrict__ csr, int ET) {
  int e = blockIdx.x * 256 + threadIdx.x;
  if (e >= ET) return;
  int d = dst[e];
  int p = atomicSub(&deg[d], 1) - 1;
  csr[off[d] + p] = src[e];
}

// --------------------------- weight pre-pack -------------------------------
__global__ __launch_bounds__(256) void pack_kernel(const float* __restrict__ W,
                                                   short* __restrict__ Wp,
                                                   int NOUT, int total) {
  int NT = NOUT >> 4;
  for (int idx = blockIdx.x * 256 + threadIdx.x; idx < total;
       idx += gridDim.x * 256) {
    int j = idx & 7;
    int lane = (idx >> 3) & 63;
    int st = idx >> 9;
    int s = st / NT, t = st - s * NT;
    int k = s * 32 + (lane >> 4) * 8 + j;
    int n = t * 16 + (lane & 15);
    Wp[idx] = (short)f2bf(W[(size_t)k * NOUT + n]);
  }
}

// ------------------------------ MFMA GEMM + fused attention logits ---------
// OUT_FP8: store C as e4m3fn (256B rows) via second LDS buffer; al epilogue
// still reads the bf16 LDS tile.
template <int K, int NOUT, bool AF32, bool OUT_FP8>
__global__ __launch_bounds__(256) void mfma_gemm(const void* __restrict__ Av,
                                                 const short* __restrict__ Bp,
                                                 short* __restrict__ Cb,
                                                 unsigned char* __restrict__ Cq,
                                                 const float* __restrict__ as,
                                                 const float* __restrict__ ad,
                                                 float* __restrict__ alsO,
                                                 float* __restrict__ aldO, int M) {
  constexpr int KS = K / 32;
  constexpr int NT = NOUT / 16;
  constexpr int RST = NOUT + 8;   // bf16 LDS row stride (shorts)
  constexpr int QST = NOUT + 16;  // fp8 LDS row stride (bytes)
  constexpr int C = NOUT / 8;     // channels per head
  __shared__ __align__(16) short lds[64 * RST];
  __shared__ __align__(16) unsigned char ldsq[OUT_FP8 ? 64 * QST : 16];
  const int tid = threadIdx.x;
  const int wave = tid >> 6, lane = tid & 63;
  const int lo = lane & 15, hi = lane >> 4;
  const int rowA = blockIdx.x * 64 + wave * 16 + lo;
  const bool inb = rowA < M;

  f32x4 acc[NT];
#pragma unroll
  for (int t = 0; t < NT; ++t) acc[t] = (f32x4){0.f, 0.f, 0.f, 0.f};

#pragma unroll
  for (int s = 0; s < KS; ++s) {
    bf16x8 af;
    if constexpr (AF32) {
      const float* Ap = (const float*)Av;
      float v[8];
      if (inb) {
        const float4 x0 = *(const float4*)&Ap[(size_t)rowA * K + s * 32 + hi * 8];
        const float4 x1 = *(const float4*)&Ap[(size_t)rowA * K + s * 32 + hi * 8 + 4];
        v[0] = x0.x; v[1] = x0.y; v[2] = x0.z; v[3] = x0.w;
        v[4] = x1.x; v[5] = x1.y; v[6] = x1.z; v[7] = x1.w;
      } else {
#pragma unroll
        for (int j = 0; j < 8; ++j) v[j] = 0.f;
      }
#pragma unroll
      for (int j = 0; j < 8; ++j) af[j] = (short)f2bf(v[j]);
    } else {
      const short* Ab = (const short*)Av;
      if (inb) {
        af = *(const bf16x8*)&Ab[(size_t)rowA * K + s * 32 + hi * 8];
      } else {
#pragma unroll
        for (int j = 0; j < 8; ++j) af[j] = 0;
      }
    }
#pragma unroll
    for (int t = 0; t < NT; ++t) {
      bf16x8 bf = *(const bf16x8*)&Bp[((size_t)(s * NT + t) * 64 + lane) * 8];
      acc[t] = __builtin_amdgcn_mfma_f32_16x16x32_bf16(af, bf, acc[t], 0, 0, 0);
    }
  }

#pragma unroll
  for (int t = 0; t < NT; ++t)
#pragma unroll
    for (int r = 0; r < 4; ++r) {
      int row = wave * 16 + hi * 4 + r;
      lds[row * RST + t * 16 + lo] = (short)f2bf(acc[t][r]);
      if constexpr (OUT_FP8)
        ldsq[row * QST + t * 16 + lo] = fp8enc(acc[t][r]);
    }
  __syncthreads();

  if constexpr (OUT_FP8) {
    // coalesced fp8 store: 64 rows x 256 B = 1024 x 16B
#pragma unroll
    for (int i = 0; i < (64 * NOUT / 16) / 256; ++i) {
      int v = i * 256 + tid;
      int r = v >> 4;
      int c = v & 15;
      int grow = blockIdx.x * 64 + r;
      if (grow < M)
        *(float4*)&Cq[(size_t)grow * NOUT + c * 16] =
            *(const float4*)&ldsq[r * QST + c * 16];
    }
  } else {
    constexpr int VECS = 64 * NOUT / 8;
#pragma unroll
    for (int i = 0; i < VECS / 256; ++i) {
      int v = i * 256 + tid;
      int r = v / (NOUT / 8);
      int c = v % (NOUT / 8);
      int grow = blockIdx.x * 64 + r;
      if (grow < M)
        *(float4*)&Cb[(size_t)grow * NOUT + c * 8] =
            *(const float4*)&lds[r * RST + c * 8];
    }
  }

  // fused al epilogue (reads bf16 LDS tile)
  constexpr int SEGS = NOUT / 64;
  if (tid < 64 * SEGS) {
    int r = tid / SEGS, seg = tid % SEGS;
    int grow = blockIdx.x * 64 + r;
    float ps[8], pd[8];
#pragma unroll
    for (int k = 0; k < 8; ++k) { ps[k] = 0.f; pd[k] = 0.f; }
#pragma unroll
    for (int k = 0; k < 8; ++k) {
      int b = seg + SEGS * k;
      u16x8 u = *(const u16x8*)&lds[r * RST + b * 8];
#pragma unroll
      for (int j = 0; j < 8; ++j) {
        float hv = bf2f(u[j]);
        ps[k] = fmaf(hv, as[k * C + seg * 8 + j], ps[k]);
        pd[k] = fmaf(hv, ad[k * C + seg * 8 + j], pd[k]);
      }
    }
#pragma unroll
    for (int d = 1; d < SEGS; d <<= 1)
#pragma unroll
      for (int k = 0; k < 8; ++k) {
        ps[k] += __shfl_xor(ps[k], d);
        pd[k] += __shfl_xor(pd[k], d);
      }
    if (seg == 0 && grow < M) {
      *(float4*)&alsO[(size_t)grow * 8] = make_float4(ps[0], ps[1], ps[2], ps[3]);
      *(float4*)&alsO[(size_t)grow * 8 + 4] = make_float4(ps[4], ps[5], ps[6], ps[7]);
      *(float4*)&aldO[(size_t)grow * 8] = make_float4(pd[0], pd[1], pd[2], pd[3]);
      *(float4*)&aldO[(size_t)grow * 8 + 4] = make_float4(pd[4], pd[5], pd[6], pd[7]);
    }
  }
}

// ------------------------- layer-1 aggregation (fp8 gather) ----------------
// One wave per dst node; 32 lanes/edge (8 fp8 ch each), 2 streams, 2x unroll.
// Single pass: acc += exp(e)*h, ws += exp(e); normalize at end.
__global__ __launch_bounds__(256) void agg1_kernel(const unsigned char* __restrict__ hq,
                                                   const float* __restrict__ als,
                                                   const float* __restrict__ ald,
                                                   const int* __restrict__ off,
                                                   const int* __restrict__ csr,
                                                   const float* __restrict__ bias,
                                                   short* __restrict__ outb, int N) {
  int wid = blockIdx.x * 4 + (threadIdx.x >> 6);
  if (wid >= N) return;
  int lane = threadIdx.x & 63;
  int rs = off[wid], re = off[wid + 1];
  int es = lane >> 5;       // 2 edge streams
  int gl = lane & 31;       // 8 channels each
  int head = gl >> 2;
  float aldv = ald[wid * 8 + head];

  float acc[8];
#pragma unroll
  for (int j = 0; j < 8; ++j) acc[j] = 0.f;
  float ws = 0.f;

  int i = rs + es;
  for (; i + 2 < re; i += 4) {
    int s0 = csr[i], s1 = csr[i + 2];
    float e0 = als[s0 * 8 + head] + aldv;
    float e1 = als[s1 * 8 + head] + aldv;
    uint2 u0 = *(const uint2*)&hq[(size_t)s0 * 256 + gl * 8];
    uint2 u1 = *(const uint2*)&hq[(size_t)s1 * 256 + gl * 8];
    e0 = e0 > 0.f ? e0 : 0.2f * e0;
    e1 = e1 > 0.f ? e1 : 0.2f * e1;
    float w0 = __expf(e0), w1 = __expf(e1);
    ws += w0 + w1;
    float d0a[4], d0b[4], d1a[4], d1b[4];
    fp8dec4(u0.x, d0a); fp8dec4(u0.y, d0b);
    fp8dec4(u1.x, d1a); fp8dec4(u1.y, d1b);
#pragma unroll
    for (int j = 0; j < 4; ++j) {
      acc[j] = fmaf(w0, d0a[j], acc[j]);
      acc[j + 4] = fmaf(w0, d0b[j], acc[j + 4]);
      acc[j] = fmaf(w1, d1a[j], acc[j]);
      acc[j + 4] = fmaf(w1, d1b[j], acc[j + 4]);
    }
  }
  if (i < re) {
    int s0 = csr[i];
    float e0 = als[s0 * 8 + head] + aldv;
    uint2 u0 = *(const uint2*)&hq[(size_t)s0 * 256 + gl * 8];
    e0 = e0 > 0.f ? e0 : 0.2f * e0;
    float w0 = __expf(e0);
    ws += w0;
    float d0a[4], d0b[4];
    fp8dec4(u0.x, d0a); fp8dec4(u0.y, d0b);
#pragma unroll
    for (int j = 0; j < 4; ++j) {
      acc[j] = fmaf(w0, d0a[j], acc[j]);
      acc[j + 4] = fmaf(w0, d0b[j], acc[j + 4]);
    }
  }

  ws += __shfl_xor(ws, 32);
#pragma unroll
  for (int j = 0; j < 8; ++j) acc[j] += __shfl_xor(acc[j], 32);
  float inv = 1.f / ws;

  if (lane < 32) {
    u16x8 o;
#pragma unroll
    for (int j = 0; j < 8; ++j) {
      float v = acc[j] * inv + bias[gl * 8 + j];
      o[j] = f2bf(v > 0.f ? v : expm1f(v));  // ELU
    }
    *(u16x8*)&outb[(size_t)wid * 256 + gl * 8] = o;
  }
}

// ------------------------- layer-2 aggregation (bf16 gather) ---------------
__global__ __launch_bounds__(256) void agg2_kernel(const short* __restrict__ hb,
                                                   const float* __restrict__ als,
                                                   const float* __restrict__ ald,
                                                   const int* __restrict__ off,
                                                   const int* __restrict__ csr,
                                                   const float* __restrict__ bias,
                                                   float* __restrict__ out, int N) {
  constexpr int LPG = 16;  // lanes per edge
  constexpr int NS = 4;    // edge streams
  int wid = blockIdx.x * 4 + (threadIdx.x >> 6);
  if (wid >= N) return;
  int lane = threadIdx.x & 63;
  int rs = off[wid], re = off[wid + 1];
  int es = lane / LPG;
  int gl = lane & (LPG - 1);
  int head = gl >> 1;
  float aldv = ald[wid * 8 + head];

  float acc[8];
#pragma unroll
  for (int j = 0; j < 8; ++j) acc[j] = 0.f;
  float ws = 0.f;

  int i = rs + es;
  for (; i + NS < re; i += 2 * NS) {
    int s0 = csr[i], s1 = csr[i + NS];
    float e0 = als[s0 * 8 + head] + aldv;
    float e1 = als[s1 * 8 + head] + aldv;
    u16x8 u0 = *(const u16x8*)&hb[(size_t)s0 * 128 + gl * 8];
    u16x8 u1 = *(const u16x8*)&hb[(size_t)s1 * 128 + gl * 8];
    e0 = e0 > 0.f ? e0 : 0.2f * e0;
    e1 = e1 > 0.f ? e1 : 0.2f * e1;
    float w0 = __expf(e0), w1 = __expf(e1);
    ws += w0 + w1;
#pragma unroll
    for (int j = 0; j < 8; ++j)
      acc[j] = fmaf(w1, bf2f(u1[j]), fmaf(w0, bf2f(u0[j]), acc[j]));
  }
  if (i < re) {
    int s0 = csr[i];
    float e0 = als[s0 * 8 + head] + aldv;
    u16x8 u0 = *(const u16x8*)&hb[(size_t)s0 * 128 + gl * 8];
    e0 = e0 > 0.f ? e0 : 0.2f * e0;
    float w0 = __expf(e0);
    ws += w0;
#pragma unroll
    for (int j = 0; j < 8; ++j) acc[j] = fmaf(w0, bf2f(u0[j]), acc[j]);
  }

#pragma unroll
  for (int d = LPG; d < 64; d <<= 1) {
    ws += __shfl_xor(ws, d);
#pragma unroll
    for (int j = 0; j < 8; ++j) acc[j] += __shfl_xor(acc[j], d);
  }
  float inv = 1.f / ws;

  // normalize, mean over heads (gl = 2h + p), log_softmax over 16 channels
#pragma unroll
  for (int j = 0; j < 8; ++j) acc[j] *= inv;
#pragma unroll
  for (int d = 2; d <= 8; d <<= 1)
#pragma unroll
    for (int j = 0; j < 8; ++j) acc[j] += __shfl_xor(acc[j], d);
  int p = gl & 1;
  float v[8];
#pragma unroll
  for (int j = 0; j < 8; ++j) v[j] = acc[j] * 0.125f + bias[p * 8 + j];
  float m = v[0];
#pragma unroll
  for (int j = 1; j < 8; ++j) m = fmaxf(m, v[j]);
  m = fmaxf(m, __shfl_xor(m, 1));
  float se = 0.f;
#pragma unroll
  for (int j = 0; j < 8; ++j) se += __expf(v[j] - m);
  se += __shfl_xor(se, 1);
  float lse = m + logf(se);
  if (lane < 2) {
    *(float4*)&out[(size_t)wid * 16 + p * 8] =
        make_float4(v[0] - lse, v[1] - lse, v[2] - lse, v[3] - lse);
    *(float4*)&out[(size_t)wid * 16 + p * 8 + 4] =
        make_float4(v[4] - lse, v[5] - lse, v[6] - lse, v[7] - lse);
  }
}

// ---------------------------------------------------------------------------

extern "C" void kernel_launch(void* const* d_in, const int* in_sizes, int n_in,
                              void* d_out, int out_size, void* d_ws, size_t ws_size,
                              hipStream_t stream) {
  const float* x = (const float*)d_in[0];
  const void* ei = d_in[1];
  const float* W1 = (const float*)d_in[2];
  const float* as1 = (const float*)d_in[3];
  const float* ad1 = (const float*)d_in[4];
  const float* b1 = (const float*)d_in[5];
  const float* W2 = (const float*)d_in[6];
  const float* as2 = (const float*)d_in[7];
  const float* ad2 = (const float*)d_in[8];
  const float* b2 = (const float*)d_in[9];
  float* out = (float*)d_out;

  const int N = out_size / 16;    // 100000
  const int E = in_sizes[1] / 2;  // 800000
  const int ET = E + N;

  char* p = (char*)d_ws;
  auto alloc = [&](size_t bytes) {
    char* r = p;
    p += (bytes + 255) & ~(size_t)255;
    return (void*)r;
  };
  unsigned char* h1q = (unsigned char*)alloc((size_t)N * 256);  // fp8 L1 rows
  short* hactb = (short*)alloc((size_t)N * 256 * 2);            // ELU out bf16
  short* h2b = (short*)alloc((size_t)N * 128 * 2);              // L2 rows bf16
  float* als = (float*)alloc((size_t)N * 8 * 4);
  float* ald = (float*)alloc((size_t)N * 8 * 4);
  int* src32 = (int*)alloc((size_t)ET * 4);
  int* dst32 = (int*)alloc((size_t)ET * 4);
  int* csr = (int*)alloc((size_t)ET * 4);
  int* deg = (int*)alloc((size_t)N * 4);
  int* off = (int*)alloc((size_t)(N + 1) * 4);
  int* bsum = (int*)alloc(256 * 4);
  int* flag = (int*)alloc(256);
  short* W1p = (short*)alloc(128 * 256 * 2);
  short* W2p = (short*)alloc(256 * 128 * 2);

  hipMemsetAsync(deg, 0, (size_t)N * 4, stream);
  hipMemsetAsync(flag, 0, 4, stream);

  detect_kernel<<<1, 256, 0, stream>>>((const int*)ei, E, flag);
  int gridET = (ET + 255) / 256;
  extract_kernel<<<gridET, 256, 0, stream>>>(ei, E, N, flag, src32, dst32, deg);
  int nscan = (N + 2047) / 2048;
  scan_a<<<nscan, 256, 0, stream>>>(deg, off, bsum, N);
  scan_b<<<1, 64, 0, stream>>>(bsum, nscan);
  scan_c<<<(N + 256) / 256, 256, 0, stream>>>(off, bsum, N);
  fill_kernel<<<gridET, 256, 0, stream>>>(src32, dst32, off, deg, csr, ET);

  pack_kernel<<<128, 256, 0, stream>>>(W1, W1p, 256, 128 * 256);
  pack_kernel<<<128, 256, 0, stream>>>(W2, W2p, 128, 256 * 128);

  int gemmGrid = (N + 63) / 64;
  int nodeGrid = (N + 3) / 4;

  mfma_gemm<128, 256, true, true><<<gemmGrid, 256, 0, stream>>>(
      x, W1p, nullptr, h1q, as1, ad1, als, ald, N);
  agg1_kernel<<<nodeGrid, 256, 0, stream>>>(h1q, als, ald, off, csr, b1, hactb, N);
  mfma_gemm<256, 128, false, false><<<gemmGrid, 256, 0, stream>>>(
      hactb, W2p, h2b, nullptr, as2, ad2, als, ald, N);
  agg2_kernel<<<nodeGrid, 256, 0, stream>>>(h2b, als, ald, off, csr, b2, out, N);
}